// Round 5
// baseline (1991.396 us; speedup 1.0000x reference)
//
#include <hip/hip_runtime.h>
#include <math.h>

#define NNODES 100000
typedef unsigned short bf16_t;

// ---------- bf16 helpers ----------
__device__ __forceinline__ float bf_lo(unsigned u) { return __uint_as_float(u << 16); }
__device__ __forceinline__ float bf_hi(unsigned u) { return __uint_as_float(u & 0xffff0000u); }
__device__ __forceinline__ bf16_t f2bf(float f) {
  unsigned u = __float_as_uint(f);
  return (bf16_t)((u + 0x7fffu + ((u >> 16) & 1u)) >> 16);
}
__device__ __forceinline__ float leaky(float v) { return fmaxf(v, 0.2f * v); }

// ---------- merged GEMM: XL/XR[n, ncols](bf16) = in[n,64] @ {Wl,Wr}[64, col0:+ncols] ----------
__global__ __launch_bounds__(256) void gemm2(const float* __restrict__ in,
                                             const float* __restrict__ Wl,
                                             const float* __restrict__ Wr,
                                             bf16_t* __restrict__ XL,
                                             bf16_t* __restrict__ XR,
                                             int n, int fo, int col0, int ncols) {
  __shared__ float sW[2][64][64];
  __shared__ float sX[16][64];
  int ct = blockIdx.y * 64;
  for (int i = threadIdx.x; i < 64 * 64; i += 256) {
    int k = i >> 6, c = i & 63;
    sW[0][k][c] = Wl[k * fo + col0 + ct + c];
    sW[1][k][c] = Wr[k * fo + col0 + ct + c];
  }
  int r0 = blockIdx.x * 16;
  for (int i = threadIdx.x; i < 16 * 64; i += 256) {
    int r = i >> 6, k = i & 63;
    sX[r][k] = (r0 + r < n) ? in[(size_t)(r0 + r) * 64 + k] : 0.f;
  }
  __syncthreads();
  int c = threadIdx.x & 63, rr = threadIdx.x >> 6;
  float aL[4] = {0.f, 0.f, 0.f, 0.f}, aR[4] = {0.f, 0.f, 0.f, 0.f};
  for (int k = 0; k < 64; ++k) {
    float wl = sW[0][k][c], wr = sW[1][k][c];
#pragma unroll
    for (int r = 0; r < 4; ++r) {
      float xv = sX[rr * 4 + r][k];
      aL[r] += xv * wl;
      aR[r] += xv * wr;
    }
  }
#pragma unroll
  for (int r = 0; r < 4; ++r) {
    int row = r0 + rr * 4 + r;
    if (row < n) {
      XL[(size_t)row * ncols + ct + c] = f2bf(aL[r]);
      XR[(size_t)row * ncols + ct + c] = f2bf(aR[r]);
    }
  }
}

// ---------- CSR build ----------
__global__ void zeroi(int* __restrict__ p, int n) {
  int i = blockIdx.x * blockDim.x + threadIdx.x;
  if (i < n) p[i] = 0;
}
__global__ void hist(const int* __restrict__ ei, int E, int* __restrict__ cnt) {
  int e = blockIdx.x * blockDim.x + threadIdx.x;
  if (e < E) atomicAdd(&cnt[ei[E + e]], 1);
}
__global__ void scan1(const int* __restrict__ cnt, int n,
                      int* __restrict__ scn, int* __restrict__ bsum) {
  __shared__ int sh[256];
  int t = threadIdx.x, i = blockIdx.x * 256 + t;
  int v = (i < n) ? cnt[i] : 0;
  sh[t] = v;
  __syncthreads();
  for (int off = 1; off < 256; off <<= 1) {
    int x = (t >= off) ? sh[t - off] : 0;
    __syncthreads();
    sh[t] += x;
    __syncthreads();
  }
  if (i < n) scn[i] = sh[t];
  if (t == 255) bsum[blockIdx.x] = sh[255];
}
__global__ void scan2(int* __restrict__ bsum, int nb) {
  __shared__ int sh[512];
  int t = threadIdx.x;
  sh[t] = (t < nb) ? bsum[t] : 0;
  __syncthreads();
  for (int off = 1; off < 512; off <<= 1) {
    int x = (t >= off) ? sh[t - off] : 0;
    __syncthreads();
    sh[t] += x;
    __syncthreads();
  }
  if (t < nb) bsum[t] = sh[t];
}
__global__ void scan3(const int* __restrict__ scn, const int* __restrict__ cnt,
                      const int* __restrict__ bsum, int n,
                      int* __restrict__ RS, int* __restrict__ cur) {
  int i = blockIdx.x * blockDim.x + threadIdx.x;
  if (i >= n) return;
  int b = i >> 8;
  int pre = (b > 0) ? bsum[b - 1] : 0;
  int incl = scn[i] + pre;
  RS[i + 1] = incl;
  cur[i] = incl - cnt[i];
  if (i == 0) RS[0] = 0;
}
__global__ void scat(const int* __restrict__ ei, int E,
                     int* __restrict__ cur, int* __restrict__ SRC) {
  int e = blockIdx.x * blockDim.x + threadIdx.x;
  if (e >= E) return;
  int d = ei[E + e];
  int pos = atomicAdd(&cur[d], 1);
  SRC[pos] = ei[e];
}

// ---------- fused layers 0/1 (C=8 concat): 2 dsts per wave, lane=2 channels ----------
__global__ __launch_bounds__(256) void fused01(const bf16_t* __restrict__ xl,
                                               const bf16_t* __restrict__ xr,
                                               const float* __restrict__ att, // [8][8]
                                               const int* __restrict__ RS,
                                               const int* __restrict__ SRC,
                                               const float* __restrict__ bias,
                                               float* __restrict__ curbuf,
                                               int n, int addres) {
  int l = threadIdx.x & 63;
  int ll = l & 31;
  int d = blockIdx.x * 8 + ((threadIdx.x >> 6) << 1) + (l >> 5);
  int dd = (d < n) ? d : 0;
  float a0 = att[2 * ll], a1 = att[2 * ll + 1];
  unsigned ur = ((const unsigned*)xr)[(size_t)dd * 32 + ll];
  float xr0 = bf_lo(ur), xr1 = bf_hi(ur);
  int rs = RS[dd], re = RS[dd + 1];
  int cnt = (d < n) ? (re - rs + 1) : 0;   // self loop + edges
  int maxcnt = max(cnt, __shfl_xor(cnt, 32));
  float m = -1e30f, s = 0.f, ac0 = 0.f, ac1 = 0.f;
  int nsid = (rs < re) ? SRC[rs] : dd;
  unsigned u = ((const unsigned*)xl)[(size_t)dd * 32 + ll];
  for (int j = 0;;) {
    unsigned un = ((const unsigned*)xl)[(size_t)nsid * 32 + ll];
    int i2 = rs + j + 1;
    int nn = (i2 < re) ? SRC[i2] : dd;
    float x0 = bf_lo(u), x1 = bf_hi(u);
    float t = leaky(x0 + xr0) * a0 + leaky(x1 + xr1) * a1;
    t += __shfl_xor(t, 1);
    t += __shfl_xor(t, 2);
    if (j >= cnt) t = -1e30f;                 // masked lane: contributes 0
    if (__any(t > m + 8.f)) {                 // rare exact rescale
      float nm = fmaxf(m, t);
      float e0 = __expf(m - nm);
      s *= e0; ac0 *= e0; ac1 *= e0; m = nm;
    }
    float e1 = __expf(t - m);
    s += e1;
    ac0 += e1 * x0;
    ac1 += e1 * x1;
    ++j;
    if (j >= maxcnt) break;
    u = un;
    nsid = nn;
  }
  if (d < n) {
    float inv = 1.f / (s + 1e-16f);
    float v0 = ac0 * inv + bias[2 * ll];
    float v1 = ac1 * inv + bias[2 * ll + 1];
    v0 = v0 > 0.f ? v0 : expm1f(v0);
    v1 = v1 > 0.f ? v1 : expm1f(v1);
    float2* pc = (float2*)(curbuf + (size_t)d * 64 + 2 * ll);
    if (addres) {
      float2 pr = *pc;
      v0 += pr.x;
      v1 += pr.y;
    }
    *pc = make_float2(v0, v1);
  }
}

// ---------- fused layer 2 (4-head block, mean over heads): 2 dsts/wave, lane=8 ch ----------
__global__ __launch_bounds__(256) void fused2(const bf16_t* __restrict__ xl,
                                              const bf16_t* __restrict__ xr,
                                              const float* __restrict__ att, // [8][64]
                                              const int* __restrict__ RS,
                                              const int* __restrict__ SRC,
                                              const float* __restrict__ bias,
                                              float* __restrict__ accbuf,
                                              float* __restrict__ outbuf,
                                              int n, int h0, int pass) {
  int l = threadIdx.x & 63;
  int ll = l & 31;
  int d = blockIdx.x * 8 + ((threadIdx.x >> 6) << 1) + (l >> 5);
  int dd = (d < n) ? d : 0;
  int h = ll >> 3, c0 = (ll & 7) * 8;
  const float* ap = att + (h0 + h) * 64 + c0;
  float a[8];
#pragma unroll
  for (int k = 0; k < 8; ++k) a[k] = ap[k];
  uint4 ur = ((const uint4*)xr)[(size_t)dd * 32 + ll];
  float r[8] = {bf_lo(ur.x), bf_hi(ur.x), bf_lo(ur.y), bf_hi(ur.y),
                bf_lo(ur.z), bf_hi(ur.z), bf_lo(ur.w), bf_hi(ur.w)};
  int rs = RS[dd], re = RS[dd + 1];
  int cnt = (d < n) ? (re - rs + 1) : 0;
  int maxcnt = max(cnt, __shfl_xor(cnt, 32));
  float m = -1e30f, s = 0.f;
  float ac[8] = {0.f, 0.f, 0.f, 0.f, 0.f, 0.f, 0.f, 0.f};
  int nsid = (rs < re) ? SRC[rs] : dd;
  uint4 u = ((const uint4*)xl)[(size_t)dd * 32 + ll];
  for (int j = 0;;) {
    uint4 un = ((const uint4*)xl)[(size_t)nsid * 32 + ll];
    int i2 = rs + j + 1;
    int nn = (i2 < re) ? SRC[i2] : dd;
    float x[8] = {bf_lo(u.x), bf_hi(u.x), bf_lo(u.y), bf_hi(u.y),
                  bf_lo(u.z), bf_hi(u.z), bf_lo(u.w), bf_hi(u.w)};
    float t = 0.f;
#pragma unroll
    for (int k = 0; k < 8; ++k) t += leaky(x[k] + r[k]) * a[k];
    t += __shfl_xor(t, 1);
    t += __shfl_xor(t, 2);
    t += __shfl_xor(t, 4);
    if (j >= cnt) t = -1e30f;
    if (__any(t > m + 8.f)) {
      float nm = fmaxf(m, t);
      float e0 = __expf(m - nm);
      s *= e0;
#pragma unroll
      for (int k = 0; k < 8; ++k) ac[k] *= e0;
      m = nm;
    }
    float e1 = __expf(t - m);
    s += e1;
#pragma unroll
    for (int k = 0; k < 8; ++k) ac[k] += e1 * x[k];
    ++j;
    if (j >= maxcnt) break;
    u = un;
    nsid = nn;
  }
  float inv = 1.f / (s + 1e-16f);
  float v[8];
#pragma unroll
  for (int k = 0; k < 8; ++k) {
    v[k] = ac[k] * inv;
    v[k] += __shfl_xor(v[k], 8);    // sum the 4 heads of this block
    v[k] += __shfl_xor(v[k], 16);
  }
  if (ll < 8 && d < n) {
    float* pa = accbuf + (size_t)d * 64 + ll * 8;
    if (pass == 0) {
      *(float4*)pa = make_float4(v[0], v[1], v[2], v[3]);
      *(float4*)(pa + 4) = make_float4(v[4], v[5], v[6], v[7]);
    } else {
      float4 p0 = *(float4*)pa;
      float4 p1 = *(float4*)(pa + 4);
      const float* bp = bias + ll * 8;
      float4 o0, o1;
      o0.x = (p0.x + v[0]) * 0.125f + bp[0];
      o0.y = (p0.y + v[1]) * 0.125f + bp[1];
      o0.z = (p0.z + v[2]) * 0.125f + bp[2];
      o0.w = (p0.w + v[3]) * 0.125f + bp[3];
      o1.x = (p1.x + v[4]) * 0.125f + bp[4];
      o1.y = (p1.y + v[5]) * 0.125f + bp[5];
      o1.z = (p1.z + v[6]) * 0.125f + bp[6];
      o1.w = (p1.w + v[7]) * 0.125f + bp[7];
      float* po = outbuf + (size_t)d * 64 + ll * 8;
      *(float4*)po = o0;
      *(float4*)(po + 4) = o1;
    }
  }
}

extern "C" void kernel_launch(void* const* d_in, const int* in_sizes, int n_in,
                              void* d_out, int out_size, void* d_ws, size_t ws_size,
                              hipStream_t stream) {
  const float* x = (const float*)d_in[0];
  const int* ei = (const int*)d_in[1];
  const float* Wmat[3][2] = {
      {(const float*)d_in[2], (const float*)d_in[3]},
      {(const float*)d_in[6], (const float*)d_in[7]},
      {(const float*)d_in[10], (const float*)d_in[11]}};
  const float* att[3] = {(const float*)d_in[4], (const float*)d_in[8],
                         (const float*)d_in[12]};
  const float* bias[3] = {(const float*)d_in[5], (const float*)d_in[9],
                          (const float*)d_in[13]};
  const int N = NNODES;
  int E = in_sizes[1] / 2;

  // ---- workspace layout (~162 MB) ----
  char* p = (char*)d_ws;
  auto alloc = [&](size_t bytes) {
    char* r = p;
    p += (bytes + 255) & ~(size_t)255;
    return r;
  };
  float* CUR = (float*)alloc((size_t)N * 64 * 4);
  float* ACC = (float*)alloc((size_t)N * 64 * 4);
  bf16_t* XL = (bf16_t*)alloc((size_t)N * 256 * 2);
  bf16_t* XR = (bf16_t*)alloc((size_t)N * 256 * 2);
  int* RS = (int*)alloc((size_t)(N + 1) * 4);
  int* CNT = (int*)alloc((size_t)N * 4);
  int* CURS = (int*)alloc((size_t)N * 4);
  int* SCN = (int*)alloc((size_t)N * 4);
  int* BSUM = (int*)alloc(512 * 4);
  int* SRC = (int*)alloc((size_t)E * 4);

  const int nb = (N + 255) / 256;
  const int geblk = (E + 255) / 256;
  const int gnode = (N + 7) / 8;    // 8 dsts per 256-thread block (2 per wave)
  const int gx16 = (N + 15) / 16;

  // ---- CSR build (once, shared by all 3 layers) ----
  zeroi<<<nb, 256, 0, stream>>>(CNT, N);
  hist<<<geblk, 256, 0, stream>>>(ei, E, CNT);
  scan1<<<nb, 256, 0, stream>>>(CNT, N, SCN, BSUM);
  scan2<<<1, 512, 0, stream>>>(BSUM, nb);
  scan3<<<nb, 256, 0, stream>>>(SCN, CNT, BSUM, N, RS, CURS);
  scat<<<geblk, 256, 0, stream>>>(ei, E, CURS, SRC);

  // ---- layers 0 and 1 (C=8, concat) ----
  for (int layer = 0; layer < 2; ++layer) {
    const float* in = (layer == 0) ? x : CUR;
    gemm2<<<dim3(gx16, 1), 256, 0, stream>>>(in, Wmat[layer][0], Wmat[layer][1],
                                             XL, XR, N, 64, 0, 64);
    fused01<<<gnode, 256, 0, stream>>>(XL, XR, att[layer], RS, SRC, bias[layer],
                                       CUR, N, layer);
  }

  // ---- layer 2 (C=64, mean over 8 heads; two 4-head passes) ----
  for (int hb = 0; hb < 2; ++hb) {
    gemm2<<<dim3(gx16, 4), 256, 0, stream>>>(CUR, Wmat[2][0], Wmat[2][1],
                                             XL, XR, N, 512, hb * 256, 256);
    fused2<<<gnode, 256, 0, stream>>>(XL, XR, att[2], RS, SRC, bias[2],
                                      ACC, (float*)d_out, N, hb * 4, hb);
  }
}

// Round 6
// 779.991 us; speedup vs baseline: 2.5531x; 2.5531x over previous
//
#include <hip/hip_runtime.h>
#include <math.h>

#define NNODES 100000
typedef unsigned short bf16_t;

typedef __attribute__((ext_vector_type(8))) short bf16x8;
typedef __attribute__((ext_vector_type(4))) float f32x4;

// ---------- bf16 helpers ----------
__device__ __forceinline__ float bf_lo(unsigned u) { return __uint_as_float(u << 16); }
__device__ __forceinline__ float bf_hi(unsigned u) { return __uint_as_float(u & 0xffff0000u); }
__device__ __forceinline__ bf16_t f2bf(float f) {
  unsigned u = __float_as_uint(f);
  return (bf16_t)((u + 0x7fffu + ((u >> 16) & 1u)) >> 16);
}
__device__ __forceinline__ float leaky(float v) { return fmaxf(v, 0.2f * v); }

#define LDK 68  // padded LDS k-stride (bf16 elems): 136B -> banks 2 apart, ~2-way max

// ---------- MFMA GEMM: XL/XR[n, ncols](bf16) = in[n,64] @ {Wl,Wr}[64, col0+ct : +64] ----------
// block = 256 thr (4 waves); block tile 64 rows x 64 cols; wave w: rows 16w..16w+15.
__global__ __launch_bounds__(256) void gemm_mfma(const float* __restrict__ in,
                                                 const float* __restrict__ Wl,
                                                 const float* __restrict__ Wr,
                                                 bf16_t* __restrict__ XL,
                                                 bf16_t* __restrict__ XR,
                                                 int n, int fo, int col0, int ncols) {
  __shared__ bf16_t sX[64][LDK];  // [row][k]
  __shared__ bf16_t sL[64][LDK];  // W transposed: [col][k]
  __shared__ bf16_t sR[64][LDK];
  int r0 = blockIdx.x * 64;
  int ct = blockIdx.y * 64;
  for (int i = threadIdx.x; i < 64 * 64; i += 256) {
    int r = i >> 6, k = i & 63;
    float v = (r0 + r < n) ? in[(size_t)(r0 + r) * 64 + k] : 0.f;
    sX[r][k] = f2bf(v);
  }
  for (int i = threadIdx.x; i < 64 * 64; i += 256) {
    int k = i >> 6, c = i & 63;
    int gc = col0 + ct + c;
    sL[c][k] = f2bf(Wl[k * fo + gc]);
    sR[c][k] = f2bf(Wr[k * fo + gc]);
  }
  __syncthreads();
  int w = threadIdx.x >> 6, l = threadIdx.x & 63;
  int l16 = l & 15, kg = l >> 4;  // kg in 0..3
  // A fragments (rows 16w+l16, k = kg*8 + {0..7} + 32*t)
  bf16x8 a0 = *(const bf16x8*)&sX[w * 16 + l16][kg * 8];
  bf16x8 a1 = *(const bf16x8*)&sX[w * 16 + l16][kg * 8 + 32];
  f32x4 accL[4], accR[4];
#pragma unroll
  for (int nt = 0; nt < 4; ++nt) {
#pragma unroll
    for (int r = 0; r < 4; ++r) { accL[nt][r] = 0.f; accR[nt][r] = 0.f; }
  }
#pragma unroll
  for (int nt = 0; nt < 4; ++nt) {
    bf16x8 bl0 = *(const bf16x8*)&sL[nt * 16 + l16][kg * 8];
    bf16x8 bl1 = *(const bf16x8*)&sL[nt * 16 + l16][kg * 8 + 32];
    bf16x8 br0 = *(const bf16x8*)&sR[nt * 16 + l16][kg * 8];
    bf16x8 br1 = *(const bf16x8*)&sR[nt * 16 + l16][kg * 8 + 32];
    accL[nt] = __builtin_amdgcn_mfma_f32_16x16x32_bf16(a0, bl0, accL[nt], 0, 0, 0);
    accL[nt] = __builtin_amdgcn_mfma_f32_16x16x32_bf16(a1, bl1, accL[nt], 0, 0, 0);
    accR[nt] = __builtin_amdgcn_mfma_f32_16x16x32_bf16(a0, br0, accR[nt], 0, 0, 0);
    accR[nt] = __builtin_amdgcn_mfma_f32_16x16x32_bf16(a1, br1, accR[nt], 0, 0, 0);
  }
  // D layout: col = l&15, row = (l>>4)*4 + reg
#pragma unroll
  for (int nt = 0; nt < 4; ++nt) {
#pragma unroll
    for (int r = 0; r < 4; ++r) {
      int grow = r0 + w * 16 + kg * 4 + r;
      if (grow < n) {
        size_t o = (size_t)grow * ncols + ct + nt * 16 + l16;
        XL[o] = f2bf(accL[nt][r]);
        XR[o] = f2bf(accR[nt][r]);
      }
    }
  }
}

// ---------- CSR build ----------
__global__ void zeroi(int* __restrict__ p, int n) {
  int i = blockIdx.x * blockDim.x + threadIdx.x;
  if (i < n) p[i] = 0;
}
__global__ void hist(const int* __restrict__ ei, int E, int* __restrict__ cnt) {
  int e = blockIdx.x * blockDim.x + threadIdx.x;
  if (e < E) atomicAdd(&cnt[ei[E + e]], 1);
}
__global__ void scan1(const int* __restrict__ cnt, int n,
                      int* __restrict__ scn, int* __restrict__ bsum) {
  __shared__ int sh[256];
  int t = threadIdx.x, i = blockIdx.x * 256 + t;
  int v = (i < n) ? cnt[i] : 0;
  sh[t] = v;
  __syncthreads();
  for (int off = 1; off < 256; off <<= 1) {
    int x = (t >= off) ? sh[t - off] : 0;
    __syncthreads();
    sh[t] += x;
    __syncthreads();
  }
  if (i < n) scn[i] = sh[t];
  if (t == 255) bsum[blockIdx.x] = sh[255];
}
__global__ void scan2(int* __restrict__ bsum, int nb) {
  __shared__ int sh[512];
  int t = threadIdx.x;
  sh[t] = (t < nb) ? bsum[t] : 0;
  __syncthreads();
  for (int off = 1; off < 512; off <<= 1) {
    int x = (t >= off) ? sh[t - off] : 0;
    __syncthreads();
    sh[t] += x;
    __syncthreads();
  }
  if (t < nb) bsum[t] = sh[t];
}
__global__ void scan3(const int* __restrict__ scn, const int* __restrict__ cnt,
                      const int* __restrict__ bsum, int n,
                      int* __restrict__ RS, int* __restrict__ cur) {
  int i = blockIdx.x * blockDim.x + threadIdx.x;
  if (i >= n) return;
  int b = i >> 8;
  int pre = (b > 0) ? bsum[b - 1] : 0;
  int incl = scn[i] + pre;
  RS[i + 1] = incl;
  cur[i] = incl - cnt[i];
  if (i == 0) RS[0] = 0;
}
__global__ void scat(const int* __restrict__ ei, int E,
                     int* __restrict__ cur, int* __restrict__ SRC) {
  int e = blockIdx.x * blockDim.x + threadIdx.x;
  if (e >= E) return;
  int d = ei[E + e];
  int pos = atomicAdd(&cur[d], 1);
  SRC[pos] = ei[e];
}

// ---------- fused layers 0/1 (C=8 concat): 2 dsts per wave, lane=2 channels ----------
__global__ __launch_bounds__(256) void fused01(const bf16_t* __restrict__ xl,
                                               const bf16_t* __restrict__ xr,
                                               const float* __restrict__ att, // [8][8]
                                               const int* __restrict__ RS,
                                               const int* __restrict__ SRC,
                                               const float* __restrict__ bias,
                                               float* __restrict__ curbuf,
                                               int n, int addres) {
  int l = threadIdx.x & 63;
  int ll = l & 31;
  int d = blockIdx.x * 8 + ((threadIdx.x >> 6) << 1) + (l >> 5);
  int dd = (d < n) ? d : 0;
  float a0 = att[2 * ll], a1 = att[2 * ll + 1];
  unsigned ur = ((const unsigned*)xr)[(size_t)dd * 32 + ll];
  float xr0 = bf_lo(ur), xr1 = bf_hi(ur);
  int rs = RS[dd], re = RS[dd + 1];
  int cnt = (d < n) ? (re - rs + 1) : 0;   // self loop + edges
  int maxcnt = max(cnt, __shfl_xor(cnt, 32));
  float m = -1e30f, s = 0.f, ac0 = 0.f, ac1 = 0.f;
  int nsid = (rs < re) ? SRC[rs] : dd;
  unsigned u = ((const unsigned*)xl)[(size_t)dd * 32 + ll];
  for (int j = 0;;) {
    unsigned un = ((const unsigned*)xl)[(size_t)nsid * 32 + ll];
    int i2 = rs + j + 1;
    int nn = (i2 < re) ? SRC[i2] : dd;
    float x0 = bf_lo(u), x1 = bf_hi(u);
    float t = leaky(x0 + xr0) * a0 + leaky(x1 + xr1) * a1;
    t += __shfl_xor(t, 1);
    t += __shfl_xor(t, 2);
    if (j >= cnt) t = -1e30f;                 // masked lane: contributes 0
    if (__any(t > m + 8.f)) {                 // rare exact rescale
      float nm = fmaxf(m, t);
      float e0 = __expf(m - nm);
      s *= e0; ac0 *= e0; ac1 *= e0; m = nm;
    }
    float e1 = __expf(t - m);
    s += e1;
    ac0 += e1 * x0;
    ac1 += e1 * x1;
    ++j;
    if (j >= maxcnt) break;
    u = un;
    nsid = nn;
  }
  if (d < n) {
    float inv = 1.f / (s + 1e-16f);
    float v0 = ac0 * inv + bias[2 * ll];
    float v1 = ac1 * inv + bias[2 * ll + 1];
    v0 = v0 > 0.f ? v0 : expm1f(v0);
    v1 = v1 > 0.f ? v1 : expm1f(v1);
    float2* pc = (float2*)(curbuf + (size_t)d * 64 + 2 * ll);
    if (addres) {
      float2 pr = *pc;
      v0 += pr.x;
      v1 += pr.y;
    }
    *pc = make_float2(v0, v1);
  }
}

// ---------- fused layer 2 (4-head block, mean over heads): 2 dsts/wave, lane=8 ch ----------
__global__ __launch_bounds__(256) void fused2(const bf16_t* __restrict__ xl,
                                              const bf16_t* __restrict__ xr,
                                              const float* __restrict__ att, // [8][64]
                                              const int* __restrict__ RS,
                                              const int* __restrict__ SRC,
                                              const float* __restrict__ bias,
                                              float* __restrict__ accbuf,
                                              float* __restrict__ outbuf,
                                              int n, int h0, int pass) {
  int l = threadIdx.x & 63;
  int ll = l & 31;
  int d = blockIdx.x * 8 + ((threadIdx.x >> 6) << 1) + (l >> 5);
  int dd = (d < n) ? d : 0;
  int h = ll >> 3, c0 = (ll & 7) * 8;
  const float* ap = att + (h0 + h) * 64 + c0;
  float a[8];
#pragma unroll
  for (int k = 0; k < 8; ++k) a[k] = ap[k];
  uint4 ur = ((const uint4*)xr)[(size_t)dd * 32 + ll];
  float r[8] = {bf_lo(ur.x), bf_hi(ur.x), bf_lo(ur.y), bf_hi(ur.y),
                bf_lo(ur.z), bf_hi(ur.z), bf_lo(ur.w), bf_hi(ur.w)};
  int rs = RS[dd], re = RS[dd + 1];
  int cnt = (d < n) ? (re - rs + 1) : 0;
  int maxcnt = max(cnt, __shfl_xor(cnt, 32));
  float m = -1e30f, s = 0.f;
  float ac[8] = {0.f, 0.f, 0.f, 0.f, 0.f, 0.f, 0.f, 0.f};
  int nsid = (rs < re) ? SRC[rs] : dd;
  uint4 u = ((const uint4*)xl)[(size_t)dd * 32 + ll];
  for (int j = 0;;) {
    uint4 un = ((const uint4*)xl)[(size_t)nsid * 32 + ll];
    int i2 = rs + j + 1;
    int nn = (i2 < re) ? SRC[i2] : dd;
    float x[8] = {bf_lo(u.x), bf_hi(u.x), bf_lo(u.y), bf_hi(u.y),
                  bf_lo(u.z), bf_hi(u.z), bf_lo(u.w), bf_hi(u.w)};
    float t = 0.f;
#pragma unroll
    for (int k = 0; k < 8; ++k) t += leaky(x[k] + r[k]) * a[k];
    t += __shfl_xor(t, 1);
    t += __shfl_xor(t, 2);
    t += __shfl_xor(t, 4);
    if (j >= cnt) t = -1e30f;
    if (__any(t > m + 8.f)) {
      float nm = fmaxf(m, t);
      float e0 = __expf(m - nm);
      s *= e0;
#pragma unroll
      for (int k = 0; k < 8; ++k) ac[k] *= e0;
      m = nm;
    }
    float e1 = __expf(t - m);
    s += e1;
#pragma unroll
    for (int k = 0; k < 8; ++k) ac[k] += e1 * x[k];
    ++j;
    if (j >= maxcnt) break;
    u = un;
    nsid = nn;
  }
  float inv = 1.f / (s + 1e-16f);
  float v[8];
#pragma unroll
  for (int k = 0; k < 8; ++k) {
    v[k] = ac[k] * inv;
    v[k] += __shfl_xor(v[k], 8);    // sum the 4 heads of this block
    v[k] += __shfl_xor(v[k], 16);
  }
  if (ll < 8 && d < n) {
    float* pa = accbuf + (size_t)d * 64 + ll * 8;
    if (pass == 0) {
      *(float4*)pa = make_float4(v[0], v[1], v[2], v[3]);
      *(float4*)(pa + 4) = make_float4(v[4], v[5], v[6], v[7]);
    } else {
      float4 p0 = *(float4*)pa;
      float4 p1 = *(float4*)(pa + 4);
      const float* bp = bias + ll * 8;
      float4 o0, o1;
      o0.x = (p0.x + v[0]) * 0.125f + bp[0];
      o0.y = (p0.y + v[1]) * 0.125f + bp[1];
      o0.z = (p0.z + v[2]) * 0.125f + bp[2];
      o0.w = (p0.w + v[3]) * 0.125f + bp[3];
      o1.x = (p1.x + v[4]) * 0.125f + bp[4];
      o1.y = (p1.y + v[5]) * 0.125f + bp[5];
      o1.z = (p1.z + v[6]) * 0.125f + bp[6];
      o1.w = (p1.w + v[7]) * 0.125f + bp[7];
      float* po = outbuf + (size_t)d * 64 + ll * 8;
      *(float4*)po = o0;
      *(float4*)(po + 4) = o1;
    }
  }
}

extern "C" void kernel_launch(void* const* d_in, const int* in_sizes, int n_in,
                              void* d_out, int out_size, void* d_ws, size_t ws_size,
                              hipStream_t stream) {
  const float* x = (const float*)d_in[0];
  const int* ei = (const int*)d_in[1];
  const float* Wmat[3][2] = {
      {(const float*)d_in[2], (const float*)d_in[3]},
      {(const float*)d_in[6], (const float*)d_in[7]},
      {(const float*)d_in[10], (const float*)d_in[11]}};
  const float* att[3] = {(const float*)d_in[4], (const float*)d_in[8],
                         (const float*)d_in[12]};
  const float* bias[3] = {(const float*)d_in[5], (const float*)d_in[9],
                          (const float*)d_in[13]};
  const int N = NNODES;
  int E = in_sizes[1] / 2;

  // ---- workspace layout (~162 MB) ----
  char* p = (char*)d_ws;
  auto alloc = [&](size_t bytes) {
    char* r = p;
    p += (bytes + 255) & ~(size_t)255;
    return r;
  };
  float* CUR = (float*)alloc((size_t)N * 64 * 4);
  float* ACC = (float*)alloc((size_t)N * 64 * 4);
  bf16_t* XL = (bf16_t*)alloc((size_t)N * 256 * 2);
  bf16_t* XR = (bf16_t*)alloc((size_t)N * 256 * 2);
  int* RS = (int*)alloc((size_t)(N + 1) * 4);
  int* CNT = (int*)alloc((size_t)N * 4);
  int* CURS = (int*)alloc((size_t)N * 4);
  int* SCN = (int*)alloc((size_t)N * 4);
  int* BSUM = (int*)alloc(512 * 4);
  int* SRC = (int*)alloc((size_t)E * 4);

  const int nb = (N + 255) / 256;
  const int geblk = (E + 255) / 256;
  const int gnode = (N + 7) / 8;    // 8 dsts per 256-thread block (2 per wave)
  const int gx64 = (N + 63) / 64;   // MFMA gemm row tiles

  // ---- CSR build (once, shared by all 3 layers) ----
  zeroi<<<nb, 256, 0, stream>>>(CNT, N);
  hist<<<geblk, 256, 0, stream>>>(ei, E, CNT);
  scan1<<<nb, 256, 0, stream>>>(CNT, N, SCN, BSUM);
  scan2<<<1, 512, 0, stream>>>(BSUM, nb);
  scan3<<<nb, 256, 0, stream>>>(SCN, CNT, BSUM, N, RS, CURS);
  scat<<<geblk, 256, 0, stream>>>(ei, E, CURS, SRC);

  // ---- layers 0 and 1 (C=8, concat) ----
  for (int layer = 0; layer < 2; ++layer) {
    const float* in = (layer == 0) ? x : CUR;
    gemm_mfma<<<dim3(gx64, 1), 256, 0, stream>>>(in, Wmat[layer][0], Wmat[layer][1],
                                                 XL, XR, N, 64, 0, 64);
    fused01<<<gnode, 256, 0, stream>>>(XL, XR, att[layer], RS, SRC, bias[layer],
                                       CUR, N, layer);
  }

  // ---- layer 2 (C=64, mean over 8 heads; two 4-head passes) ----
  for (int hb = 0; hb < 2; ++hb) {
    gemm_mfma<<<dim3(gx64, 4), 256, 0, stream>>>(CUR, Wmat[2][0], Wmat[2][1],
                                                 XL, XR, N, 512, hb * 256, 256);
    fused2<<<gnode, 256, 0, stream>>>(XL, XR, att[2], RS, SRC, bias[2],
                                      ACC, (float*)d_out, N, hb * 4, hb);
  }
}

// Round 7
// 622.653 us; speedup vs baseline: 3.1982x; 1.2527x over previous
//
#include <hip/hip_runtime.h>
#include <math.h>

#define NNODES 100000
typedef unsigned short bf16_t;

typedef __attribute__((ext_vector_type(8))) short bf16x8;
typedef __attribute__((ext_vector_type(4))) float f32x4;

// ---------- bf16 helpers ----------
__device__ __forceinline__ float bf_lo(unsigned u) { return __uint_as_float(u << 16); }
__device__ __forceinline__ float bf_hi(unsigned u) { return __uint_as_float(u & 0xffff0000u); }
__device__ __forceinline__ bf16_t f2bf(float f) {
  unsigned u = __float_as_uint(f);
  return (bf16_t)((u + 0x7fffu + ((u >> 16) & 1u)) >> 16);
}
__device__ __forceinline__ float leaky(float v) { return fmaxf(v, 0.2f * v); }

#define LDK 68  // padded LDS k-stride (bf16): 2-way bank aliasing max (free)

// ---------- MFMA GEMM: XL/XR[n, ncols](bf16) = in[n,64] @ {Wl,Wr}[64, col0+ct : +64] ----------
__global__ __launch_bounds__(256) void gemm_mfma(const float* __restrict__ in,
                                                 const float* __restrict__ Wl,
                                                 const float* __restrict__ Wr,
                                                 bf16_t* __restrict__ XL,
                                                 bf16_t* __restrict__ XR,
                                                 int n, int fo, int col0, int ncols) {
  __shared__ bf16_t sX[64][LDK];  // [row][k]
  __shared__ bf16_t sL[64][LDK];  // W transposed: [col][k]
  __shared__ bf16_t sR[64][LDK];
  int r0 = blockIdx.x * 64;
  int ct = blockIdx.y * 64;
  for (int i = threadIdx.x; i < 64 * 64; i += 256) {
    int r = i >> 6, k = i & 63;
    float v = (r0 + r < n) ? in[(size_t)(r0 + r) * 64 + k] : 0.f;
    sX[r][k] = f2bf(v);
  }
  for (int i = threadIdx.x; i < 64 * 64; i += 256) {
    int k = i >> 6, c = i & 63;
    int gc = col0 + ct + c;
    sL[c][k] = f2bf(Wl[k * fo + gc]);
    sR[c][k] = f2bf(Wr[k * fo + gc]);
  }
  __syncthreads();
  int w = threadIdx.x >> 6, l = threadIdx.x & 63;
  int l16 = l & 15, kg = l >> 4;
  bf16x8 a0 = *(const bf16x8*)&sX[w * 16 + l16][kg * 8];
  bf16x8 a1 = *(const bf16x8*)&sX[w * 16 + l16][kg * 8 + 32];
  f32x4 accL[4], accR[4];
#pragma unroll
  for (int nt = 0; nt < 4; ++nt) {
#pragma unroll
    for (int r = 0; r < 4; ++r) { accL[nt][r] = 0.f; accR[nt][r] = 0.f; }
  }
#pragma unroll
  for (int nt = 0; nt < 4; ++nt) {
    bf16x8 bl0 = *(const bf16x8*)&sL[nt * 16 + l16][kg * 8];
    bf16x8 bl1 = *(const bf16x8*)&sL[nt * 16 + l16][kg * 8 + 32];
    bf16x8 br0 = *(const bf16x8*)&sR[nt * 16 + l16][kg * 8];
    bf16x8 br1 = *(const bf16x8*)&sR[nt * 16 + l16][kg * 8 + 32];
    accL[nt] = __builtin_amdgcn_mfma_f32_16x16x32_bf16(a0, bl0, accL[nt], 0, 0, 0);
    accL[nt] = __builtin_amdgcn_mfma_f32_16x16x32_bf16(a1, bl1, accL[nt], 0, 0, 0);
    accR[nt] = __builtin_amdgcn_mfma_f32_16x16x32_bf16(a0, br0, accR[nt], 0, 0, 0);
    accR[nt] = __builtin_amdgcn_mfma_f32_16x16x32_bf16(a1, br1, accR[nt], 0, 0, 0);
  }
#pragma unroll
  for (int nt = 0; nt < 4; ++nt) {
#pragma unroll
    for (int r = 0; r < 4; ++r) {
      int grow = r0 + w * 16 + kg * 4 + r;
      if (grow < n) {
        size_t o = (size_t)grow * ncols + ct + nt * 16 + l16;
        XL[o] = f2bf(accL[nt][r]);
        XR[o] = f2bf(accR[nt][r]);
      }
    }
  }
}

// ---------- CSR build (atomic-free scatter via ranks) ----------
__global__ void zeroi(int* __restrict__ p, int n) {
  int i = blockIdx.x * blockDim.x + threadIdx.x;
  if (i < n) p[i] = 0;
}
__global__ void histrank(const int* __restrict__ ei, int E,
                         int* __restrict__ cnt, unsigned char* __restrict__ rank) {
  int e = blockIdx.x * blockDim.x + threadIdx.x;
  if (e < E) rank[e] = (unsigned char)atomicAdd(&cnt[ei[E + e]], 1);
}
// per-block inclusive scan of cnt -> scn (= RS+1), block sums -> bsum
__global__ void scan1(const int* __restrict__ cnt, int n,
                      int* __restrict__ scn, int* __restrict__ bsum) {
  __shared__ int sh[256];
  int t = threadIdx.x, i = blockIdx.x * 256 + t;
  int v = (i < n) ? cnt[i] : 0;
  sh[t] = v;
  __syncthreads();
  for (int off = 1; off < 256; off <<= 1) {
    int x = (t >= off) ? sh[t - off] : 0;
    __syncthreads();
    sh[t] += x;
    __syncthreads();
  }
  if (i < n) scn[i] = sh[t];
  if (t == 255) bsum[blockIdx.x] = sh[255];
}
__global__ void scan2(int* __restrict__ bsum, int nb) {
  __shared__ int sh[512];
  int t = threadIdx.x;
  sh[t] = (t < nb) ? bsum[t] : 0;
  __syncthreads();
  for (int off = 1; off < 512; off <<= 1) {
    int x = (t >= off) ? sh[t - off] : 0;
    __syncthreads();
    sh[t] += x;
    __syncthreads();
  }
  if (t < nb) bsum[t] = sh[t];
}
__global__ void scan3(int* __restrict__ RS, const int* __restrict__ bsum, int n) {
  int i = blockIdx.x * blockDim.x + threadIdx.x;
  if (i >= n) return;
  int b = i >> 8;
  int pre = (b > 0) ? bsum[b - 1] : 0;
  RS[i + 1] += pre;
  if (i == 0) RS[0] = 0;
}
__global__ void scat2(const int* __restrict__ ei, int E,
                      const int* __restrict__ RS,
                      const unsigned char* __restrict__ rank,
                      int* __restrict__ SRC) {
  int e = blockIdx.x * blockDim.x + threadIdx.x;
  if (e >= E) return;
  int d = ei[E + e];
  SRC[RS[d] + (int)rank[e]] = ei[e];
}

// ---------- fused layers 0/1 (C=8 concat): 4 dsts per wave, lane = 4 channels ----------
__global__ __launch_bounds__(256) void fused01(const bf16_t* __restrict__ xl,
                                               const bf16_t* __restrict__ xr,
                                               const float* __restrict__ att, // [8][8]
                                               const int* __restrict__ RS,
                                               const int* __restrict__ SRC,
                                               const float* __restrict__ bias,
                                               float* __restrict__ curbuf,
                                               int n, int addres) {
  int l = threadIdx.x & 63;
  int q = l & 15;  // channel quad: ch 4q..4q+3; head = q>>1
  int d = blockIdx.x * 16 + ((threadIdx.x >> 6) << 2) + (l >> 4);
  int dd = (d < n) ? d : 0;
  float a0 = att[4 * q], a1 = att[4 * q + 1], a2 = att[4 * q + 2], a3 = att[4 * q + 3];
  uint2 ur = ((const uint2*)xr)[(size_t)dd * 16 + q];
  float r0 = bf_lo(ur.x), r1 = bf_hi(ur.x), r2 = bf_lo(ur.y), r3 = bf_hi(ur.y);
  int rs = RS[dd], re = RS[dd + 1];
  int cnt = (d < n) ? (re - rs + 1) : 0;  // self loop + edges
  int mc = max(cnt, __shfl_xor(cnt, 16));
  mc = max(mc, __shfl_xor(mc, 32));
  float m = -1e30f, s = 0.f, ac0 = 0.f, ac1 = 0.f, ac2 = 0.f, ac3 = 0.f;
  int nsid = (rs < re) ? SRC[rs] : dd;
  uint2 u = ((const uint2*)xl)[(size_t)dd * 16 + q];
  for (int j = 0;;) {
    uint2 un = ((const uint2*)xl)[(size_t)nsid * 16 + q];
    int i2 = rs + j + 1;
    int nn = (i2 < re) ? SRC[i2] : dd;
    float x0 = bf_lo(u.x), x1 = bf_hi(u.x), x2 = bf_lo(u.y), x3 = bf_hi(u.y);
    float t = leaky(x0 + r0) * a0 + leaky(x1 + r1) * a1 +
              leaky(x2 + r2) * a2 + leaky(x3 + r3) * a3;
    t += __shfl_xor(t, 1);  // 8-ch head spans lane pair
    if (j >= cnt) t = -1e30f;
    if (__any(t > m + 8.f)) {  // rare exact rescale
      float nm = fmaxf(m, t);
      float e0 = __expf(m - nm);
      s *= e0; ac0 *= e0; ac1 *= e0; ac2 *= e0; ac3 *= e0; m = nm;
    }
    float e1 = __expf(t - m);
    s += e1;
    ac0 += e1 * x0; ac1 += e1 * x1; ac2 += e1 * x2; ac3 += e1 * x3;
    ++j;
    if (j >= mc) break;
    u = un;
    nsid = nn;
  }
  if (d < n) {
    float inv = 1.f / (s + 1e-16f);
    float v0 = ac0 * inv + bias[4 * q];
    float v1 = ac1 * inv + bias[4 * q + 1];
    float v2 = ac2 * inv + bias[4 * q + 2];
    float v3 = ac3 * inv + bias[4 * q + 3];
    v0 = v0 > 0.f ? v0 : expm1f(v0);
    v1 = v1 > 0.f ? v1 : expm1f(v1);
    v2 = v2 > 0.f ? v2 : expm1f(v2);
    v3 = v3 > 0.f ? v3 : expm1f(v3);
    float4* pc = (float4*)(curbuf + (size_t)d * 64 + 4 * q);
    if (addres) {
      float4 pr = *pc;
      v0 += pr.x; v1 += pr.y; v2 += pr.z; v3 += pr.w;
    }
    *pc = make_float4(v0, v1, v2, v3);
  }
}

// ---------- fused layer 2 (4-head block, mean over heads): 2 dsts/wave, lane=8 ch ----------
__global__ __launch_bounds__(256) void fused2(const bf16_t* __restrict__ xl,
                                              const bf16_t* __restrict__ xr,
                                              const float* __restrict__ att, // [8][64]
                                              const int* __restrict__ RS,
                                              const int* __restrict__ SRC,
                                              const float* __restrict__ bias,
                                              float* __restrict__ accbuf,
                                              float* __restrict__ outbuf,
                                              int n, int h0, int pass) {
  int l = threadIdx.x & 63;
  int ll = l & 31;
  int d = blockIdx.x * 8 + ((threadIdx.x >> 6) << 1) + (l >> 5);
  int dd = (d < n) ? d : 0;
  int h = ll >> 3, c0 = (ll & 7) * 8;
  const float* ap = att + (h0 + h) * 64 + c0;
  float a[8];
#pragma unroll
  for (int k = 0; k < 8; ++k) a[k] = ap[k];
  uint4 ur = ((const uint4*)xr)[(size_t)dd * 32 + ll];
  float r[8] = {bf_lo(ur.x), bf_hi(ur.x), bf_lo(ur.y), bf_hi(ur.y),
                bf_lo(ur.z), bf_hi(ur.z), bf_lo(ur.w), bf_hi(ur.w)};
  int rs = RS[dd], re = RS[dd + 1];
  int cnt = (d < n) ? (re - rs + 1) : 0;
  int maxcnt = max(cnt, __shfl_xor(cnt, 32));
  float m = -1e30f, s = 0.f;
  float ac[8] = {0.f, 0.f, 0.f, 0.f, 0.f, 0.f, 0.f, 0.f};
  int nsid = (rs < re) ? SRC[rs] : dd;
  uint4 u = ((const uint4*)xl)[(size_t)dd * 32 + ll];
  for (int j = 0;;) {
    uint4 un = ((const uint4*)xl)[(size_t)nsid * 32 + ll];
    int i2 = rs + j + 1;
    int nn = (i2 < re) ? SRC[i2] : dd;
    float x[8] = {bf_lo(u.x), bf_hi(u.x), bf_lo(u.y), bf_hi(u.y),
                  bf_lo(u.z), bf_hi(u.z), bf_lo(u.w), bf_hi(u.w)};
    float t = 0.f;
#pragma unroll
    for (int k = 0; k < 8; ++k) t += leaky(x[k] + r[k]) * a[k];
    t += __shfl_xor(t, 1);
    t += __shfl_xor(t, 2);
    t += __shfl_xor(t, 4);
    if (j >= cnt) t = -1e30f;
    if (__any(t > m + 8.f)) {
      float nm = fmaxf(m, t);
      float e0 = __expf(m - nm);
      s *= e0;
#pragma unroll
      for (int k = 0; k < 8; ++k) ac[k] *= e0;
      m = nm;
    }
    float e1 = __expf(t - m);
    s += e1;
#pragma unroll
    for (int k = 0; k < 8; ++k) ac[k] += e1 * x[k];
    ++j;
    if (j >= maxcnt) break;
    u = un;
    nsid = nn;
  }
  float inv = 1.f / (s + 1e-16f);
  float v[8];
#pragma unroll
  for (int k = 0; k < 8; ++k) {
    v[k] = ac[k] * inv;
    v[k] += __shfl_xor(v[k], 8);    // sum the 4 heads of this block
    v[k] += __shfl_xor(v[k], 16);
  }
  if (ll < 8 && d < n) {
    float* pa = accbuf + (size_t)d * 64 + ll * 8;
    if (pass == 0) {
      *(float4*)pa = make_float4(v[0], v[1], v[2], v[3]);
      *(float4*)(pa + 4) = make_float4(v[4], v[5], v[6], v[7]);
    } else {
      float4 p0 = *(float4*)pa;
      float4 p1 = *(float4*)(pa + 4);
      const float* bp = bias + ll * 8;
      float4 o0, o1;
      o0.x = (p0.x + v[0]) * 0.125f + bp[0];
      o0.y = (p0.y + v[1]) * 0.125f + bp[1];
      o0.z = (p0.z + v[2]) * 0.125f + bp[2];
      o0.w = (p0.w + v[3]) * 0.125f + bp[3];
      o1.x = (p1.x + v[4]) * 0.125f + bp[4];
      o1.y = (p1.y + v[5]) * 0.125f + bp[5];
      o1.z = (p1.z + v[6]) * 0.125f + bp[6];
      o1.w = (p1.w + v[7]) * 0.125f + bp[7];
      float* po = outbuf + (size_t)d * 64 + ll * 8;
      *(float4*)po = o0;
      *(float4*)(po + 4) = o1;
    }
  }
}

extern "C" void kernel_launch(void* const* d_in, const int* in_sizes, int n_in,
                              void* d_out, int out_size, void* d_ws, size_t ws_size,
                              hipStream_t stream) {
  const float* x = (const float*)d_in[0];
  const int* ei = (const int*)d_in[1];
  const float* Wmat[3][2] = {
      {(const float*)d_in[2], (const float*)d_in[3]},
      {(const float*)d_in[6], (const float*)d_in[7]},
      {(const float*)d_in[10], (const float*)d_in[11]}};
  const float* att[3] = {(const float*)d_in[4], (const float*)d_in[8],
                         (const float*)d_in[12]};
  const float* bias[3] = {(const float*)d_in[5], (const float*)d_in[9],
                          (const float*)d_in[13]};
  const int N = NNODES;
  int E = in_sizes[1] / 2;

  // ---- workspace layout (~162.4 MB) ----
  char* p = (char*)d_ws;
  auto alloc = [&](size_t bytes) {
    char* r = p;
    p += (bytes + 255) & ~(size_t)255;
    return r;
  };
  float* CUR = (float*)alloc((size_t)N * 64 * 4);
  float* ACC = (float*)alloc((size_t)N * 64 * 4);
  bf16_t* XL = (bf16_t*)alloc((size_t)N * 256 * 2);
  bf16_t* XR = (bf16_t*)alloc((size_t)N * 256 * 2);
  int* RS = (int*)alloc((size_t)(N + 1) * 4);
  int* CNT = (int*)alloc((size_t)N * 4);
  int* BSUM = (int*)alloc(512 * 4);
  int* SRC = (int*)alloc((size_t)E * 4);
  unsigned char* RANK = (unsigned char*)alloc((size_t)E);

  const int nb = (N + 255) / 256;
  const int geblk = (E + 255) / 256;
  const int g01 = (N + 15) / 16;   // fused01: 16 dsts per block (4 per wave)
  const int g2 = (N + 7) / 8;      // fused2:  8 dsts per block (2 per wave)
  const int gx64 = (N + 63) / 64;

  // ---- CSR build (once, shared by all 3 layers) ----
  zeroi<<<nb, 256, 0, stream>>>(CNT, N);
  histrank<<<geblk, 256, 0, stream>>>(ei, E, CNT, RANK);
  scan1<<<nb, 256, 0, stream>>>(CNT, N, RS + 1, BSUM);
  scan2<<<1, 512, 0, stream>>>(BSUM, nb);
  scan3<<<nb, 256, 0, stream>>>(RS, BSUM, N);
  scat2<<<geblk, 256, 0, stream>>>(ei, E, RS, RANK, SRC);

  // ---- layers 0 and 1 (C=8, concat) ----
  for (int layer = 0; layer < 2; ++layer) {
    const float* in = (layer == 0) ? x : CUR;
    gemm_mfma<<<dim3(gx64, 1), 256, 0, stream>>>(in, Wmat[layer][0], Wmat[layer][1],
                                                 XL, XR, N, 64, 0, 64);
    fused01<<<g01, 256, 0, stream>>>(XL, XR, att[layer], RS, SRC, bias[layer],
                                     CUR, N, layer);
  }

  // ---- layer 2 (C=64, mean over 8 heads; two 4-head passes) ----
  for (int hb = 0; hb < 2; ++hb) {
    gemm_mfma<<<dim3(gx64, 4), 256, 0, stream>>>(CUR, Wmat[2][0], Wmat[2][1],
                                                 XL, XR, N, 512, hb * 256, 256);
    fused2<<<g2, 256, 0, stream>>>(XL, XR, att[2], RS, SRC, bias[2],
                                   ACC, (float*)d_out, N, hb * 4, hb);
  }
}